// Round 1
// baseline (123.268 us; speedup 1.0000x reference)
//
#include <hip/hip_runtime.h>
#include <hip/hip_bf16.h>

#define NN 1024
#define LN_EPS 1e-5f

typedef __bf16 bf16x8 __attribute__((ext_vector_type(8)));
typedef float floatx16 __attribute__((ext_vector_type(16)));
typedef float floatx4 __attribute__((ext_vector_type(4)));
typedef float floatx2 __attribute__((ext_vector_type(2)));

// Kernel 1 (blocks 0..1023, 256 thr): per-node precompute with 4 d-slices/wave.
//   Ap[i][h] = emb[i]·W1[:64,h] + b1[h]     (row-major [1024][64])
//   Bp[j][h] = emb[j]·W1[64:,h]             (row-major [1024][64] -- NEW layout,
//                                            coalesced write, vectorizable read)
//   sumA[i] = Σ_h Ap[i][h], sumB[j] = Σ_h Bp[j][h]
// Block 1024: pack W2^T into 32x32x16 MFMA A-fragment order (bf16).
__global__ __launch_bounds__(256) void precompute_ab(
    const float* __restrict__ emb, const float* __restrict__ W1,
    const float* __restrict__ b1, const float* __restrict__ W2,
    float* __restrict__ Ap, float* __restrict__ Bp,
    float* __restrict__ sumA, float* __restrict__ sumB,
    __bf16* __restrict__ Wf) {
    if (blockIdx.x == 1024) {
        // A-frag for mfma_f32_32x32x16_bf16: lane l holds A[m][k], m=l&31,
        // k = kstep*16 + (l>>5)*8 + t.  A = W2^T: A[m=h'][k] = W2[k][h'].
        int tid = threadIdx.x;
        if (tid >= 64) return;
        int m_l = tid & 31, kg = tid >> 5;
#pragma unroll
        for (int mt = 0; mt < 2; mt++)
#pragma unroll
            for (int s = 0; s < 4; s++) {
                bf16x8 f;
#pragma unroll
                for (int t = 0; t < 8; t++) {
                    int k = s * 16 + kg * 8 + t;
                    f[t] = (__bf16)W2[k * 64 + mt * 32 + m_l];
                }
                *(bf16x8*)&Wf[((mt * 4 + s) * 64 + tid) * 8] = f;
            }
        return;
    }
    __shared__ __align__(16) float e[64];
    __shared__ float pA[4][64], pB[4][64];
    int i = blockIdx.x;
    int h = threadIdx.x & 63, q = threadIdx.x >> 6;   // q = d-slice, wave-uniform
    if (threadIdx.x < 64) e[h] = emb[i * 64 + h];
    __syncthreads();
    float a = 0.f, b = 0.f;
#pragma unroll
    for (int dd = 0; dd < 16; dd++) {
        int d = q * 16 + dd;
        a = fmaf(e[d], W1[d * 64 + h], a);
        b = fmaf(e[d], W1[(64 + d) * 64 + h], b);
    }
    pA[q][h] = a;
    pB[q][h] = b;
    __syncthreads();
    if (threadIdx.x < 64) {
        float ra = pA[0][h] + pA[1][h] + pA[2][h] + pA[3][h] + b1[h];
        float rb = pB[0][h] + pB[1][h] + pB[2][h] + pB[3][h];
        Ap[i * 64 + h] = ra;
        Bp[i * 64 + h] = rb;
#pragma unroll
        for (int off = 1; off < 64; off <<= 1) {
            ra += __shfl_xor(ra, off);
            rb += __shfl_xor(rb, off);
        }
        if (h == 0) { sumA[i] = ra; sumB[i] = rb; }
    }
}

// Kernel 2: fused pair-MLP. Block = 256 thr = 4 waves. Block b: i = b>>2,
// wave w covers j in [ (b&3)*256 + w*64 , +64 ).  Lane = pair within the wave.
// Layer 2 now uses mfma_f32_32x32x16_bf16 (2x2 tiles): rows-per-lane are
// 4-contiguous -> b128 const reads; LN2/score reductions need 1 shfl_xor(32).
// Wave-uniform data (Ap row, g1/be1, sumA, b3) read via uniform global idx
// -> s_load on the SMEM pipe, no LDS staging.
__global__ __launch_bounds__(256, 4) void fused(
    const float* __restrict__ Ap, const float* __restrict__ Bp, const __bf16* __restrict__ Wf,
    const float* __restrict__ sumA, const float* __restrict__ sumB,
    const float* __restrict__ g1, const float* __restrict__ be1, const float* __restrict__ b2,
    const float* __restrict__ g2, const float* __restrict__ be2, const float* __restrict__ W3,
    const float* __restrict__ b3, const float* __restrict__ mask, float* __restrict__ out) {
    __shared__ __align__(16) float B2s[64], G2s[64], BE2s[64], W3s[64];
    __shared__ __align__(16) __bf16 h1t[4][64 * 64];  // per-wave 8KB bf16 h1 tile, XOR-swizzled

    int tid = threadIdx.x;
    int wave = tid >> 6, lane = tid & 63;
    int i = blockIdx.x >> 2;
    int j0 = (blockIdx.x & 3) * 256 + wave * 64;

    if (tid < 64) {
        B2s[tid] = b2[tid]; G2s[tid] = g2[tid];
        BE2s[tid] = be2[tid]; W3s[tid] = W3[tid];
    }
    __syncthreads();

    // ---- Stage 1: x = Ap[i] + Bp[j]  (lane = pair; 16x dwordx4 per lane) ----
    int j = j0 + lane;
    float sBj = sumB[j];
    const floatx4* bp4 = (const floatx4*)(Bp + j * 64);
    const floatx4* ap4 = (const floatx4*)(Ap + i * 64);   // uniform -> s_load
    floatx2 x2[32];
    floatx2 qa = {0.f, 0.f}, qb = {0.f, 0.f};
#pragma unroll
    for (int c = 0; c < 16; c++) {
        floatx4 bb = bp4[c];
        floatx4 aa = ap4[c];
        floatx2 v0 = {aa[0] + bb[0], aa[1] + bb[1]};   // v_pk_add_f32
        floatx2 v1 = {aa[2] + bb[2], aa[3] + bb[3]};
        x2[2 * c] = v0;
        x2[2 * c + 1] = v1;
        qa += v0 * v0;                                  // v_pk_fma_f32
        qb += v1 * v1;
    }
    floatx2 qs = qa + qb;
    float sq = qs[0] + qs[1];
    float m1 = (sumA[i] + sBj) * 0.015625f;   // mean of pre1 is linear in A,B
    float var1 = fmaf(m1, -m1, sq * 0.015625f);
    float rs1 = rsqrtf(var1 + LN_EPS);
    floatx2 p1 = {rs1, rs1};
    float ofs = -m1 * rs1;
    floatx2 o1 = {ofs, ofs};

    // ---- LN1 + ReLU -> bf16, write own row to LDS (chunk XOR-swizzle) ----
    __bf16* rowp = &h1t[wave][lane * 64];
    int sw = lane & 7;
#pragma unroll
    for (int c = 0; c < 8; c++) {
        bf16x8 fr;
#pragma unroll
        for (int t = 0; t < 4; t++) {
            floatx2 gg = *(const floatx2*)&g1[c * 8 + 2 * t];   // uniform -> s_load
            floatx2 ee = *(const floatx2*)&be1[c * 8 + 2 * t];  // uniform -> s_load
            floatx2 xn = x2[c * 4 + t] * p1 + o1;   // v_pk_fma_f32
            floatx2 y = xn * gg + ee;               // v_pk_fma_f32
            y = __builtin_elementwise_max(y, (floatx2){0.f, 0.f});
            fr[2 * t] = (__bf16)y[0];
            fr[2 * t + 1] = (__bf16)y[1];
        }
        *(bf16x8*)(rowp + ((c ^ sw) * 8)) = fr;
    }
    // wave-private tile: per-wave DS ops are in-order; drain before cross-lane reads
    asm volatile("s_waitcnt lgkmcnt(0)" ::: "memory");

    // ---- W2^T fragments (loaded after x2 is dead: keeps peak VGPR < 128) ----
    int m_l = lane & 31, kg2 = lane >> 5;
    bf16x8 afrag[2][4];
#pragma unroll
    for (int mt = 0; mt < 2; mt++)
#pragma unroll
        for (int s = 0; s < 4; s++)
            afrag[mt][s] = *(const bf16x8*)&Wf[((mt * 4 + s) * 64 + lane) * 8];

    // ---- MFMA 32x32x16: pre2^T = W2^T @ h1^T ; C rows = h', cols = pairs ----
    floatx16 acc[2][2];
#pragma unroll
    for (int a = 0; a < 2; a++)
#pragma unroll
        for (int b = 0; b < 2; b++)
#pragma unroll
            for (int r = 0; r < 16; r++) acc[a][b][r] = 0.f;

    const __bf16* wbase = &h1t[wave][0];
#pragma unroll
    for (int nt = 0; nt < 2; nt++) {
        int pair = nt * 32 + m_l;
#pragma unroll
        for (int s = 0; s < 4; s++) {
            int chunk = s * 2 + kg2;
            bf16x8 bfrag = *(const bf16x8*)(wbase + pair * 64 + ((chunk ^ (pair & 7)) * 8));
#pragma unroll
            for (int mt = 0; mt < 2; mt++)
                acc[mt][nt] = __builtin_amdgcn_mfma_f32_32x32x16_bf16(
                    afrag[mt][s], bfrag, acc[mt][nt], 0, 0, 0);
        }
    }

    float b3v = b3[0];

    // ---- Epilogue: +b2, LN2, ReLU, dot W3, mask.
    // C layout (32x32): col = lane&31 (pair), row = (reg&3) + 8*(reg>>2) + 4*kg2;
    // h' = mt*32 + row.  reg = q*4+e -> rows q*8+kg2*4+e are 4-contiguous: b128 consts.
#pragma unroll
    for (int nt = 0; nt < 2; nt++) {
        floatx2 s2v = {0.f, 0.f}, q2v = {0.f, 0.f};
#pragma unroll
        for (int mt = 0; mt < 2; mt++) {
#pragma unroll
            for (int q = 0; q < 4; q++) {
                int r0 = mt * 32 + q * 8 + kg2 * 4;
                floatx4 bq = *(const floatx4*)&B2s[r0];
                floatx2 vlo = {acc[mt][nt][q * 4 + 0] + bq[0], acc[mt][nt][q * 4 + 1] + bq[1]};
                floatx2 vhi = {acc[mt][nt][q * 4 + 2] + bq[2], acc[mt][nt][q * 4 + 3] + bq[3]};
                acc[mt][nt][q * 4 + 0] = vlo[0]; acc[mt][nt][q * 4 + 1] = vlo[1];
                acc[mt][nt][q * 4 + 2] = vhi[0]; acc[mt][nt][q * 4 + 3] = vhi[1];
                s2v += vlo; s2v += vhi;              // v_pk_add_f32
                q2v += vlo * vlo; q2v += vhi * vhi;  // v_pk_fma_f32
            }
        }
        float s2 = s2v[0] + s2v[1];
        float q2 = q2v[0] + q2v[1];
        s2 += __shfl_xor(s2, 32);   // partner lane holds the other 32 h' rows
        q2 += __shfl_xor(q2, 32);
        float m2 = s2 * 0.015625f;
        float var2 = fmaf(m2, -m2, q2 * 0.015625f);
        float rs2 = rsqrtf(var2 + LN_EPS);
        floatx2 p2 = {rs2, rs2};
        float o2s = -m2 * rs2;
        floatx2 o2 = {o2s, o2s};

        floatx2 scv = {0.f, 0.f};
#pragma unroll
        for (int mt = 0; mt < 2; mt++) {
#pragma unroll
            for (int q = 0; q < 4; q++) {
                int r0 = mt * 32 + q * 8 + kg2 * 4;
                floatx4 gq = *(const floatx4*)&G2s[r0];
                floatx4 eq = *(const floatx4*)&BE2s[r0];
                floatx4 wq = *(const floatx4*)&W3s[r0];
                floatx2 vlo = {acc[mt][nt][q * 4 + 0], acc[mt][nt][q * 4 + 1]};
                floatx2 vhi = {acc[mt][nt][q * 4 + 2], acc[mt][nt][q * 4 + 3]};
                floatx2 xlo = vlo * p2 + o2;                      // v_pk_fma_f32
                floatx2 xhi = vhi * p2 + o2;
                floatx2 ylo = xlo * (floatx2){gq[0], gq[1]} + (floatx2){eq[0], eq[1]};
                floatx2 yhi = xhi * (floatx2){gq[2], gq[3]} + (floatx2){eq[2], eq[3]};
                ylo = __builtin_elementwise_max(ylo, (floatx2){0.f, 0.f});
                yhi = __builtin_elementwise_max(yhi, (floatx2){0.f, 0.f});
                scv += ylo * (floatx2){wq[0], wq[1]};             // v_pk_fma_f32
                scv += yhi * (floatx2){wq[2], wq[3]};
            }
        }
        float sc = scv[0] + scv[1];
        sc += __shfl_xor(sc, 32);

        if (kg2 == 0) {
            int jj = j0 + nt * 32 + m_l;
            int p = i * NN + jj;
            out[p] = (i == jj) ? 0.f : (sc + b3v) * mask[p];
        }
    }
}

extern "C" void kernel_launch(void* const* d_in, const int* in_sizes, int n_in,
                              void* d_out, int out_size, void* d_ws, size_t ws_size,
                              hipStream_t stream) {
    const float* emb = (const float*)d_in[0];
    const float* mask = (const float*)d_in[1];
    const float* W1 = (const float*)d_in[2];
    const float* b1 = (const float*)d_in[3];
    const float* g1 = (const float*)d_in[4];
    const float* be1 = (const float*)d_in[5];
    const float* W2 = (const float*)d_in[6];
    const float* b2 = (const float*)d_in[7];
    const float* g2 = (const float*)d_in[8];
    const float* be2 = (const float*)d_in[9];
    const float* W3 = (const float*)d_in[10];
    const float* b3 = (const float*)d_in[11];
    float* out = (float*)d_out;

    float* Ap = (float*)d_ws;                 // 1024*64 f32 = 256 KB
    float* Bp = Ap + 1024 * 64;               // 1024*64 f32 = 256 KB (row-major [j][h])
    float* sA = Bp + 1024 * 64;               // 1024 f32 = 4 KB
    float* sB = sA + 1024;                    // 1024 f32 = 4 KB
    __bf16* Wf = (__bf16*)(sB + 1024);        // 4096 bf16 = 8 KB

    precompute_ab<<<1025, 256, 0, stream>>>(emb, W1, b1, W2, Ap, Bp, sA, sB, Wf);
    fused<<<4096, 256, 0, stream>>>(Ap, Bp, Wf, sA, sB, g1, be1, b2, g2, be2, W3, b3, mask, out);
}

// Round 2
// 113.790 us; speedup vs baseline: 1.0833x; 1.0833x over previous
//
#include <hip/hip_runtime.h>
#include <hip/hip_bf16.h>

#define NN 1024
#define LN_EPS 1e-5f

typedef __bf16 bf16x8 __attribute__((ext_vector_type(8)));
typedef float floatx16 __attribute__((ext_vector_type(16)));
typedef float floatx4 __attribute__((ext_vector_type(4)));
typedef float floatx2 __attribute__((ext_vector_type(2)));

__device__ __forceinline__ void load_lds16(const float* g, float* l) {
    __builtin_amdgcn_global_load_lds(
        (const __attribute__((address_space(1))) void*)g,
        (__attribute__((address_space(3))) void*)l, 16, 0, 0);
}

// Kernel 1 (blocks 0..1023, 256 thr): per-node precompute, 4 d-slices/wave.
//   Ap[i][h] = emb[i]·W1[:64,h] + b1[h]     (row-major [1024][64])
//   Bp[j][h] = emb[j]·W1[64:,h]             (row-major [1024][64])
//   sumA/sumB = row sums; sqA/sqB = row sums of squares (for analytic LN1 var)
// Block 1024: pack W2^T into 32x32x16 MFMA A-fragment order (bf16).
__global__ __launch_bounds__(256) void precompute_ab(
    const float* __restrict__ emb, const float* __restrict__ W1,
    const float* __restrict__ b1, const float* __restrict__ W2,
    float* __restrict__ Ap, float* __restrict__ Bp,
    float* __restrict__ sumA, float* __restrict__ sumB,
    float* __restrict__ sqA, float* __restrict__ sqB,
    __bf16* __restrict__ Wf) {
    if (blockIdx.x == 1024) {
        // A-frag for mfma_f32_32x32x16_bf16: lane l holds A[m][k], m=l&31,
        // k = s*16 + (l>>5)*8 + t.  A = W2^T: A[m=h'][k] = W2[k][h'].
        int tid = threadIdx.x;
        if (tid >= 64) return;
        int m_l = tid & 31, kg = tid >> 5;
#pragma unroll
        for (int mt = 0; mt < 2; mt++)
#pragma unroll
            for (int s = 0; s < 4; s++) {
                bf16x8 f;
#pragma unroll
                for (int t = 0; t < 8; t++) {
                    int k = s * 16 + kg * 8 + t;
                    f[t] = (__bf16)W2[k * 64 + mt * 32 + m_l];
                }
                *(bf16x8*)&Wf[((mt * 4 + s) * 64 + tid) * 8] = f;
            }
        return;
    }
    __shared__ __align__(16) float e[64];
    __shared__ float pA[4][64], pB[4][64];
    int i = blockIdx.x;
    int h = threadIdx.x & 63, q = threadIdx.x >> 6;
    if (threadIdx.x < 64) e[h] = emb[i * 64 + h];
    __syncthreads();
    float a = 0.f, b = 0.f;
#pragma unroll
    for (int dd = 0; dd < 16; dd++) {
        int d = q * 16 + dd;
        a = fmaf(e[d], W1[d * 64 + h], a);
        b = fmaf(e[d], W1[(64 + d) * 64 + h], b);
    }
    pA[q][h] = a;
    pB[q][h] = b;
    __syncthreads();
    if (threadIdx.x < 64) {
        float ra = pA[0][h] + pA[1][h] + pA[2][h] + pA[3][h] + b1[h];
        float rb = pB[0][h] + pB[1][h] + pB[2][h] + pB[3][h];
        Ap[i * 64 + h] = ra;
        Bp[i * 64 + h] = rb;
        float qa = ra * ra, qb = rb * rb;
#pragma unroll
        for (int off = 1; off < 64; off <<= 1) {
            ra += __shfl_xor(ra, off);
            rb += __shfl_xor(rb, off);
            qa += __shfl_xor(qa, off);
            qb += __shfl_xor(qb, off);
        }
        if (h == 0) { sumA[i] = ra; sumB[i] = rb; sqA[i] = qa; sqB[i] = qb; }
    }
}

// Kernel 2: fused pair-MLP. Block = 256 thr = 4 waves; block b: i = b>>3,
// j-tile = (b&7)*128.  Wave w owns 32 pairs p = w*32 + (lane&31).
// Wave stages its own 32 Bp rows into LDS via global_load_lds (coalesced 1KB
// ops, source pre-swizzled so row reads are conflict-free ds_read_b128).
// LN1 variance is analytic: sqA + 2*dot + sqB, dot via broadcast-A MFMA over
// the same tile -> no per-pair reduction, no h1 LDS round-trip: h1 is built
// directly in B-fragment registers and fed to mfma_f32_32x32x16_bf16.
__global__ __launch_bounds__(256, 4) void fused(
    const float* __restrict__ Ap, const float* __restrict__ Bp, const __bf16* __restrict__ Wf,
    const float* __restrict__ sumA, const float* __restrict__ sumB,
    const float* __restrict__ sqA, const float* __restrict__ sqB,
    const float* __restrict__ g1, const float* __restrict__ be1, const float* __restrict__ b2,
    const float* __restrict__ g2, const float* __restrict__ be2, const float* __restrict__ W3,
    const float* __restrict__ b3, const float* __restrict__ mask, float* __restrict__ out) {
    __shared__ __align__(16) float Bt[128 * 64];   // 32 KB swizzled f32 tile
    __shared__ __align__(16) float A_s[64], G1s[64], E1s[64], B2s[64], G2s[64], E2s[64], W3s[64];

    int tid = threadIdx.x;
    int wave = tid >> 6, lane = tid & 63;
    int i = blockIdx.x >> 3;
    int j0 = (blockIdx.x & 7) * 128;

    // ---- stage: wave's rows wave*32 .. +31, 16B-chunk cp holds source chunk
    // cs = (cp&8) | ((cp&7) ^ (row&7))  (involution: read uses same formula) ----
    {
        int cp = lane & 15;
#pragma unroll
        for (int o = 0; o < 8; o++) {
            int rr = wave * 32 + o * 4 + (lane >> 4);
            int cs = (cp & 8) | ((cp & 7) ^ (rr & 7));
            load_lds16(Bp + (j0 + rr) * 64 + cs * 4, Bt + (wave * 8 + o) * 256);
        }
    }
    if (tid < 64) {
        A_s[tid] = Ap[i * 64 + tid];
        G1s[tid] = g1[tid]; E1s[tid] = be1[tid];
        B2s[tid] = b2[tid]; G2s[tid] = g2[tid]; E2s[tid] = be2[tid];
        W3s[tid] = W3[tid];
    }
    __syncthreads();   // drains vmcnt(0): global_load_lds complete

    int m_l = lane & 31, kg2 = lane >> 5;
    int myp = wave * 32 + m_l;
    int myj = j0 + myp;

    float sBj = sumB[myj], qBj = sqB[myj];   // coalesced 128B per half-wave
    float sAi = sumA[i], qAi = sqA[i];       // uniform -> s_load
    float b3v = b3[0];

    // ---- granules: gr[s][q] = Bp[myp][s*16 + kg2*8 + q*4 .. +4] (swizzled read) ----
    floatx4 gr[4][2];
    const float* trow = Bt + myp * 64;
#pragma unroll
    for (int s = 0; s < 4; s++) {
        int c0 = s * 4 + kg2 * 2;
#pragma unroll
        for (int q = 0; q < 2; q++) {
            int c = c0 + q;
            int sp = (c & 8) | ((c & 7) ^ (myp & 7));
            gr[s][q] = *(const floatx4*)(trow + sp * 4);
        }
    }

    // ---- dot(Ap[i], Bp[myj]) via broadcast-A MFMA: every C row = the dot ----
    bf16x8 afragD[4];
#pragma unroll
    for (int s = 0; s < 4; s++) {
        floatx4 a0 = *(const floatx4*)(A_s + s * 16 + kg2 * 8);
        floatx4 a1 = *(const floatx4*)(A_s + s * 16 + kg2 * 8 + 4);
#pragma unroll
        for (int t = 0; t < 4; t++) { afragD[s][t] = (__bf16)a0[t]; afragD[s][4 + t] = (__bf16)a1[t]; }
    }
    floatx16 accD;
#pragma unroll
    for (int r = 0; r < 16; r++) accD[r] = 0.f;
#pragma unroll
    for (int s = 0; s < 4; s++) {
        bf16x8 bd;
#pragma unroll
        for (int q = 0; q < 2; q++)
#pragma unroll
            for (int t = 0; t < 4; t++) bd[q * 4 + t] = (__bf16)gr[s][q][t];
        accD = __builtin_amdgcn_mfma_f32_32x32x16_bf16(afragD[s], bd, accD, 0, 0, 0);
    }

    // ---- W2^T fragments (coalesced, L2-hot) ----
    bf16x8 afragW[2][4];
#pragma unroll
    for (int mt = 0; mt < 2; mt++)
#pragma unroll
        for (int s = 0; s < 4; s++)
            afragW[mt][s] = *(const bf16x8*)&Wf[((mt * 4 + s) * 64 + lane) * 8];

    // ---- analytic LN1 stats ----
    float dot = accD[0];
    float m1 = (sAi + sBj) * 0.015625f;
    float var1 = fmaf(m1, -m1, (qAi + 2.f * dot + qBj) * 0.015625f);
    float rs1 = rsqrtf(var1 + LN_EPS);
    float o1 = -m1 * rs1;
    floatx2 p1v = {rs1, rs1}, o1v = {o1, o1};

    // ---- layer 2: generate h1 in B-frag registers, feed MFMA directly ----
    floatx16 acc0, acc1;
#pragma unroll
    for (int r = 0; r < 16; r++) { acc0[r] = 0.f; acc1[r] = 0.f; }

#pragma unroll
    for (int s = 0; s < 4; s++) {
        bf16x8 bh;
#pragma unroll
        for (int q = 0; q < 2; q++) {
            floatx4 aq = *(const floatx4*)(A_s + s * 16 + kg2 * 8 + q * 4);
            floatx4 gq = *(const floatx4*)(G1s + s * 16 + kg2 * 8 + q * 4);
            floatx4 eq = *(const floatx4*)(E1s + s * 16 + kg2 * 8 + q * 4);
#pragma unroll
            for (int t2 = 0; t2 < 2; t2++) {
                floatx2 x = {gr[s][q][2 * t2] + aq[2 * t2], gr[s][q][2 * t2 + 1] + aq[2 * t2 + 1]};
                floatx2 xn = x * p1v + o1v;                     // v_pk_fma_f32
                floatx2 y = xn * (floatx2){gq[2 * t2], gq[2 * t2 + 1]} +
                            (floatx2){eq[2 * t2], eq[2 * t2 + 1]};
                y = __builtin_elementwise_max(y, (floatx2){0.f, 0.f});
                bh[q * 4 + 2 * t2] = (__bf16)y[0];
                bh[q * 4 + 2 * t2 + 1] = (__bf16)y[1];
            }
        }
        acc0 = __builtin_amdgcn_mfma_f32_32x32x16_bf16(afragW[0][s], bh, acc0, 0, 0, 0);
        acc1 = __builtin_amdgcn_mfma_f32_32x32x16_bf16(afragW[1][s], bh, acc1, 0, 0, 0);
    }

    // ---- Epilogue: +b2, LN2, ReLU, dot W3, mask.
    // C 32x32 layout: col = lane&31 (pair), row = (reg&3)+8*(reg>>2)+4*kg2 (+mt*32)
    floatx2 s2v = {0.f, 0.f}, q2v = {0.f, 0.f};
#pragma unroll
    for (int mt = 0; mt < 2; mt++) {
        floatx16& A = mt ? acc1 : acc0;
#pragma unroll
        for (int q = 0; q < 4; q++) {
            int r0 = mt * 32 + q * 8 + kg2 * 4;
            floatx4 bq = *(const floatx4*)&B2s[r0];
            floatx2 vlo = {A[q * 4 + 0] + bq[0], A[q * 4 + 1] + bq[1]};
            floatx2 vhi = {A[q * 4 + 2] + bq[2], A[q * 4 + 3] + bq[3]};
            A[q * 4 + 0] = vlo[0]; A[q * 4 + 1] = vlo[1];
            A[q * 4 + 2] = vhi[0]; A[q * 4 + 3] = vhi[1];
            s2v += vlo; s2v += vhi;
            q2v += vlo * vlo; q2v += vhi * vhi;
        }
    }
    float s2 = s2v[0] + s2v[1], q2 = q2v[0] + q2v[1];
    s2 += __shfl_xor(s2, 32);   // partner lane holds the other 32 h' rows
    q2 += __shfl_xor(q2, 32);
    float m2 = s2 * 0.015625f;
    float var2 = fmaf(m2, -m2, q2 * 0.015625f);
    float rs2 = rsqrtf(var2 + LN_EPS);
    floatx2 p2 = {rs2, rs2};
    float o2s = -m2 * rs2;
    floatx2 o2 = {o2s, o2s};

    floatx2 scv = {0.f, 0.f};
#pragma unroll
    for (int mt = 0; mt < 2; mt++) {
        floatx16& A = mt ? acc1 : acc0;
#pragma unroll
        for (int q = 0; q < 4; q++) {
            int r0 = mt * 32 + q * 8 + kg2 * 4;
            floatx4 gq = *(const floatx4*)&G2s[r0];
            floatx4 eq = *(const floatx4*)&E2s[r0];
            floatx4 wq = *(const floatx4*)&W3s[r0];
            floatx2 vlo = {A[q * 4 + 0], A[q * 4 + 1]};
            floatx2 vhi = {A[q * 4 + 2], A[q * 4 + 3]};
            floatx2 xlo = vlo * p2 + o2;
            floatx2 xhi = vhi * p2 + o2;
            floatx2 ylo = xlo * (floatx2){gq[0], gq[1]} + (floatx2){eq[0], eq[1]};
            floatx2 yhi = xhi * (floatx2){gq[2], gq[3]} + (floatx2){eq[2], eq[3]};
            ylo = __builtin_elementwise_max(ylo, (floatx2){0.f, 0.f});
            yhi = __builtin_elementwise_max(yhi, (floatx2){0.f, 0.f});
            scv += ylo * (floatx2){wq[0], wq[1]};
            scv += yhi * (floatx2){wq[2], wq[3]};
        }
    }
    float sc = scv[0] + scv[1];
    sc += __shfl_xor(sc, 32);

    if (kg2 == 0) {
        int p = i * NN + myj;
        out[p] = (i == myj) ? 0.f : (sc + b3v) * mask[p];
    }
}

extern "C" void kernel_launch(void* const* d_in, const int* in_sizes, int n_in,
                              void* d_out, int out_size, void* d_ws, size_t ws_size,
                              hipStream_t stream) {
    const float* emb = (const float*)d_in[0];
    const float* mask = (const float*)d_in[1];
    const float* W1 = (const float*)d_in[2];
    const float* b1 = (const float*)d_in[3];
    const float* g1 = (const float*)d_in[4];
    const float* be1 = (const float*)d_in[5];
    const float* W2 = (const float*)d_in[6];
    const float* b2 = (const float*)d_in[7];
    const float* g2 = (const float*)d_in[8];
    const float* be2 = (const float*)d_in[9];
    const float* W3 = (const float*)d_in[10];
    const float* b3 = (const float*)d_in[11];
    float* out = (float*)d_out;

    float* Ap = (float*)d_ws;                 // 1024*64 f32 = 256 KB
    float* Bp = Ap + 1024 * 64;               // 1024*64 f32 = 256 KB (row-major [j][h])
    float* sA = Bp + 1024 * 64;               // 1024 f32
    float* sB = sA + 1024;                    // 1024 f32
    float* qA = sB + 1024;                    // 1024 f32
    float* qB = qA + 1024;                    // 1024 f32
    __bf16* Wf = (__bf16*)(qB + 1024);        // 4096 bf16 = 8 KB

    precompute_ab<<<1025, 256, 0, stream>>>(emb, W1, b1, W2, Ap, Bp, sA, sB, qA, qB, Wf);
    fused<<<8192, 256, 0, stream>>>(Ap, Bp, Wf, sA, sB, qA, qB,
                                    g1, be1, b2, g2, be2, W3, b3, mask, out);
}